// Round 2
// baseline (666.331 us; speedup 1.0000x reference)
//
#include <hip/hip_runtime.h>
#include <math.h>

#define T_STEPS 32768
#define N_NEUR  1024
#define FILT_LEN 200
#define CHUNK   128     // scan steps per chunk
#define NCHUNK  256     // chunks (= block size of scan kernel)

__device__ __forceinline__ float waveMax(float v) {
#pragma unroll
    for (int off = 32; off > 0; off >>= 1) v = fmaxf(v, __shfl_xor(v, off));
    return v;
}
__device__ __forceinline__ float waveSum(float v) {
#pragma unroll
    for (int off = 32; off > 0; off >>= 1) v += __shfl_xor(v, off);
    return v;
}
__device__ __forceinline__ int waveSumI(int v) {
#pragma unroll
    for (int off = 32; off > 0; off >>= 1) v += __shfl_xor(v, off);
    return v;
}

// ---------------- noise: 200-tap causal FIR of noise_rand*0.2 ----------------
__global__ __launch_bounds__(256) void noise_kernel(
    const float* __restrict__ noise_rand, float* __restrict__ noise_out)
{
    __shared__ float s_filt[FILT_LEN];
    __shared__ float s_nr[256 + FILT_LEN - 1];
    const int tid = threadIdx.x;
    const int t0  = blockIdx.x * 256;

    if (tid < FILT_LEN) s_filt[tid] = expf(-((float)tid * 0.05f));
    for (int i = tid; i < 256 + FILT_LEN - 1; i += 256) {
        int k = t0 - (FILT_LEN - 1) + i;
        s_nr[i] = (k >= 0) ? noise_rand[k] * 0.2f : 0.0f;
    }
    __syncthreads();

    const int t = t0 + tid;
    float acc = 0.0f;
    // k ascending (j = t-k descending): noise[t] = sum_k nr[k]*filt[t-k]
#pragma unroll 4
    for (int j = FILT_LEN - 1; j >= 0; --j) {
        acc = fmaf(s_nr[tid + (FILT_LEN - 1) - j], s_filt[j], acc);
    }
    noise_out[t] = acc;
}

// ---------------- per-row: zero-fill out row, softmax-cumsum argmax, thr ----
__global__ __launch_bounds__(256) void rows_kernel(
    const float* __restrict__ inputs, const float* __restrict__ noise,
    const float* __restrict__ u_mult, const float* __restrict__ rand_val,
    float* __restrict__ out_spikes, float* __restrict__ thrT, int* __restrict__ idx_ws)
{
    const int t    = blockIdx.x;
    const int tid  = threadIdx.x;
    const int lane = tid & 63;
    const int wid  = tid >> 6;

    const float4* row = reinterpret_cast<const float4*>(inputs + (size_t)t * N_NEUR);
    float4 x = row[tid];

    // zero-fill this output row (poisoned 0xAA by harness); scatter fixes later
    reinterpret_cast<float4*>(out_spikes + (size_t)t * N_NEUR)[tid] =
        make_float4(0.f, 0.f, 0.f, 0.f);

    __shared__ float s_max[4], s_se[4], s_sy[4], s_wtot[4];
    __shared__ int   s_cnt[4];

    // row max of x
    float m = fmaxf(fmaxf(x.x, x.y), fmaxf(x.z, x.w));
    m = waveMax(m);
    if (lane == 0) s_max[wid] = m;
    __syncthreads();
    m = fmaxf(fmaxf(s_max[0], s_max[1]), fmaxf(s_max[2], s_max[3]));

    // softmax numerators + denominator (no noise)
    float e0 = expf(x.x - m), e1 = expf(x.y - m), e2 = expf(x.z - m), e3 = expf(x.w - m);
    float s = ((e0 + e1) + e2) + e3;
    s = waveSum(s);
    if (lane == 0) s_se[wid] = s;

    // logsumexp over y = x + noise; max(y) = fl(m + nz) by rounding monotonicity
    const float nz = noise[t];
    const float my = m + nz;
    float f0 = expf((x.x + nz) - my), f1 = expf((x.y + nz) - my);
    float f2 = expf((x.z + nz) - my), f3 = expf((x.w + nz) - my);
    float sy = ((f0 + f1) + f2) + f3;
    sy = waveSum(sy);
    if (lane == 0) s_sy[wid] = sy;
    __syncthreads();
    const float sum_e  = ((s_se[0] + s_se[1]) + s_se[2]) + s_se[3];
    const float sum_ey = ((s_sy[0] + s_sy[1]) + s_sy[2]) + s_sy[3];

    // cumsum of p = e/sum_e; first index with cumsum >= u == count of (cumsum < u)
    float p0 = e0 / sum_e, p1 = e1 / sum_e, p2 = e2 / sum_e, p3 = e3 / sum_e;
    float c0 = p0, c1 = c0 + p1, c2 = c1 + p2, c3 = c2 + p3;
    float tot = c3;
    float sc = tot;
#pragma unroll
    for (int off = 1; off < 64; off <<= 1) {
        float v = __shfl_up(sc, off);
        if (lane >= off) sc += v;
    }
    if (lane == 63) s_wtot[wid] = sc;
    __syncthreads();
    float woff = 0.0f;
    for (int w = 0; w < wid; ++w) woff += s_wtot[w];
    float prev = __shfl_up(sc, 1);
    float base = woff + ((lane == 0) ? 0.0f : prev);

    const float u = u_mult[t];
    int cnt = (int)(base + c0 < u) + (int)(base + c1 < u) +
              (int)(base + c2 < u) + (int)(base + c3 < u);
    cnt = waveSumI(cnt);
    if (lane == 0) s_cnt[wid] = cnt;
    __syncthreads();

    if (tid == 0) {
        int idx = ((s_cnt[0] + s_cnt[1]) + s_cnt[2]) + s_cnt[3];
        if (idx >= N_NEUR) idx = 0;   // all-False -> argmax returns 0
        idx_ws[t] = idx;
        float log_total = my + logf(sum_ey);
        float thr = (log_total + (float)(-6.907755278982137)) - logf(rand_val[t]);
        // transposed store for coalesced scan reads: thrT[i][c], t = c*128 + i
        thrT[(t & (CHUNK - 1)) * NCHUNK + (t >> 7)] = thr;
    }
}

// ---------------- sequential inhibition recurrence via chunked Jacobi fixpoint
// Each lane owns a 128-step chunk computed with bit-exact sequential fp32
// (separate mul then add, matching numpy). Chunk-boundary states iterate to a
// bitwise fixpoint; at the fixpoint the result equals the sequential scan.
__global__ __launch_bounds__(256) void scan_kernel(
    const float* __restrict__ thrT, float* __restrict__ inh_out,
    float* __restrict__ spike_ws)
{
    const int c = threadIdx.x;
    __shared__ float bnd[NCHUNK + 1];
    if (c == 0) bnd[0] = 0.0f;
    bnd[c + 1] = 0.0f;      // initial guess
    __syncthreads();

    const float F = 0.8187307530779818f;   // (float)exp(-DT/INH_TAU)
    for (int round = 0; round < 300; ++round) {
        float inh = bnd[c];
        float* out_base = inh_out  + (size_t)c * CHUNK;
        float* spk_base = spike_ws + (size_t)c * CHUNK;
#pragma unroll 4
        for (int i = 0; i < CHUNK; ++i) {
            float th   = thrT[i * NCHUNK + c];
            bool spike = inh < th;
            inh = __fmul_rn(inh, F);                    // no FMA contraction
            if (spike) inh = __fadd_rn(inh, 3000.0f);
            out_base[i] = inh;
            spk_base[i] = spike ? 1.0f : 0.0f;
        }
        int ch = (__float_as_uint(inh) != __float_as_uint(bnd[c + 1])) ? 1 : 0;
        __syncthreads();          // all reads of bnd done before overwrite
        bnd[c + 1] = inh;
        int any = __syncthreads_or(ch);
        if (!any) break;          // converged: this round's outputs are exact
    }
}

// ---------------- scatter the 1.0 spikes into the zeroed one-hot matrix -----
__global__ __launch_bounds__(256) void scatter_kernel(
    const float* __restrict__ spike_ws, const int* __restrict__ idx_ws,
    float* __restrict__ out_spikes)
{
    int t = blockIdx.x * 256 + threadIdx.x;
    if (spike_ws[t] != 0.0f)
        out_spikes[(size_t)t * N_NEUR + idx_ws[t]] = 1.0f;
}

extern "C" void kernel_launch(void* const* d_in, const int* in_sizes, int n_in,
                              void* d_out, int out_size, void* d_ws, size_t ws_size,
                              hipStream_t stream)
{
    const float* inputs     = (const float*)d_in[0];
    const float* noise_rand = (const float*)d_in[1];
    const float* u_mult     = (const float*)d_in[2];
    const float* rand_val   = (const float*)d_in[3];

    float* out_spk   = (float*)d_out;
    float* out_inh   = out_spk + (size_t)T_STEPS * N_NEUR;
    float* out_noise = out_inh + T_STEPS;

    float* thrT     = (float*)d_ws;
    int*   idx_ws   = (int*)((char*)d_ws + (size_t)T_STEPS * 4);
    float* spike_ws = (float*)((char*)d_ws + 2 * (size_t)T_STEPS * 4);

    noise_kernel<<<T_STEPS / 256, 256, 0, stream>>>(noise_rand, out_noise);
    rows_kernel<<<T_STEPS, 256, 0, stream>>>(inputs, out_noise, u_mult, rand_val,
                                             out_spk, thrT, idx_ws);
    scan_kernel<<<1, 256, 0, stream>>>(thrT, out_inh, spike_ws);
    scatter_kernel<<<T_STEPS / 256, 256, 0, stream>>>(spike_ws, idx_ws, out_spk);
}

// Round 3
// 380.508 us; speedup vs baseline: 1.7512x; 1.7512x over previous
//
#include <hip/hip_runtime.h>
#include <math.h>

#define T_STEPS 32768
#define N_NEUR  1024
#define FILT_LEN 200
#define CHUNK   128          // scan steps per chunk
#define NCHUNK  256          // chunks (= block size of scan kernel)
#define LDS_STRIDE 257       // [i][c] row stride, +1 pad -> bank-conflict-free

__device__ __forceinline__ float waveMax(float v) {
#pragma unroll
    for (int off = 32; off > 0; off >>= 1) v = fmaxf(v, __shfl_xor(v, off));
    return v;
}
__device__ __forceinline__ float waveSum(float v) {
#pragma unroll
    for (int off = 32; off > 0; off >>= 1) v += __shfl_xor(v, off);
    return v;
}
__device__ __forceinline__ int waveSumI(int v) {
#pragma unroll
    for (int off = 32; off > 0; off >>= 1) v += __shfl_xor(v, off);
    return v;
}

// ---------------- noise: 200-tap causal FIR of noise_rand*0.2 ----------------
__global__ __launch_bounds__(256) void noise_kernel(
    const float* __restrict__ noise_rand, float* __restrict__ noise_out)
{
    __shared__ float s_filt[FILT_LEN];
    __shared__ float s_nr[256 + FILT_LEN - 1];
    const int tid = threadIdx.x;
    const int t0  = blockIdx.x * 256;

    if (tid < FILT_LEN) s_filt[tid] = expf(-((float)tid * 0.05f));
    for (int i = tid; i < 256 + FILT_LEN - 1; i += 256) {
        int k = t0 - (FILT_LEN - 1) + i;
        s_nr[i] = (k >= 0) ? noise_rand[k] * 0.2f : 0.0f;
    }
    __syncthreads();

    const int t = t0 + tid;
    float acc = 0.0f;
#pragma unroll 4
    for (int j = FILT_LEN - 1; j >= 0; --j) {
        acc = fmaf(s_nr[tid + (FILT_LEN - 1) - j], s_filt[j], acc);
    }
    noise_out[t] = acc;
}

// ---------------- per-row (one WAVE per row): softmax-cumsum argmax + thr ----
// 4 rows per 256-thread block; all reductions are wave-local shuffles (no LDS,
// no __syncthreads). Element order within the row is (j, lane, q):
// e-index = j*256 + lane*4 + q, preserved for the cumsum prefix decomposition.
__global__ __launch_bounds__(256) void rows_kernel(
    const float* __restrict__ inputs, const float* __restrict__ noise,
    const float* __restrict__ u_mult, const float* __restrict__ rand_val,
    float* __restrict__ out_spikes, float* __restrict__ thr_out,
    int* __restrict__ idx_ws)
{
    const int wid  = threadIdx.x >> 6;
    const int lane = threadIdx.x & 63;
    const int t    = blockIdx.x * 4 + wid;

    const float4* row = reinterpret_cast<const float4*>(inputs + (size_t)t * N_NEUR);
    float4 x0 = row[lane];
    float4 x1 = row[lane + 64];
    float4 x2 = row[lane + 128];
    float4 x3 = row[lane + 192];

    // zero-fill this output row (harness poisons d_out); sparse scatter later
    float4 z = make_float4(0.f, 0.f, 0.f, 0.f);
    float4* orow = reinterpret_cast<float4*>(out_spikes + (size_t)t * N_NEUR);
    orow[lane] = z; orow[lane + 64] = z; orow[lane + 128] = z; orow[lane + 192] = z;

    // ---- row max ----
    float m = fmaxf(
        fmaxf(fmaxf(fmaxf(x0.x, x0.y), fmaxf(x0.z, x0.w)),
              fmaxf(fmaxf(x1.x, x1.y), fmaxf(x1.z, x1.w))),
        fmaxf(fmaxf(fmaxf(x2.x, x2.y), fmaxf(x2.z, x2.w)),
              fmaxf(fmaxf(x3.x, x3.y), fmaxf(x3.z, x3.w))));
    m = waveMax(m);

    // ---- softmax numerators (no noise) + denominator ----
    float e00 = expf(x0.x - m), e01 = expf(x0.y - m), e02 = expf(x0.z - m), e03 = expf(x0.w - m);
    float e10 = expf(x1.x - m), e11 = expf(x1.y - m), e12 = expf(x1.z - m), e13 = expf(x1.w - m);
    float e20 = expf(x2.x - m), e21 = expf(x2.y - m), e22 = expf(x2.z - m), e23 = expf(x2.w - m);
    float e30 = expf(x3.x - m), e31 = expf(x3.y - m), e32 = expf(x3.z - m), e33 = expf(x3.w - m);
    float s0 = ((e00 + e01) + e02) + e03;
    float s1 = ((e10 + e11) + e12) + e13;
    float s2 = ((e20 + e21) + e22) + e23;
    float s3 = ((e30 + e31) + e32) + e33;
    const float sum_e = waveSum(((s0 + s1) + s2) + s3);

    // ---- logsumexp over y = x + noise; max(y) = fl(m + nz) by monotonicity ----
    const float nz = noise[t];
    const float my = m + nz;
    float f0 = ((expf((x0.x + nz) - my) + expf((x0.y + nz) - my))
              +  expf((x0.z + nz) - my)) + expf((x0.w + nz) - my);
    float f1 = ((expf((x1.x + nz) - my) + expf((x1.y + nz) - my))
              +  expf((x1.z + nz) - my)) + expf((x1.w + nz) - my);
    float f2 = ((expf((x2.x + nz) - my) + expf((x2.y + nz) - my))
              +  expf((x2.z + nz) - my)) + expf((x2.w + nz) - my);
    float f3 = ((expf((x3.x + nz) - my) + expf((x3.y + nz) - my))
              +  expf((x3.z + nz) - my)) + expf((x3.w + nz) - my);
    const float sum_ey = waveSum(((f0 + f1) + f2) + f3);

    // ---- p = e / sum_e (true division, per reference), hierarchical prefix ----
    float p00 = e00 / sum_e, p01 = e01 / sum_e, p02 = e02 / sum_e, p03 = e03 / sum_e;
    float p10 = e10 / sum_e, p11 = e11 / sum_e, p12 = e12 / sum_e, p13 = e13 / sum_e;
    float p20 = e20 / sum_e, p21 = e21 / sum_e, p22 = e22 / sum_e, p23 = e23 / sum_e;
    float p30 = e30 / sum_e, p31 = e31 / sum_e, p32 = e32 / sum_e, p33 = e33 / sum_e;

    // within-group prefixes
    float c00 = p00, c01 = c00 + p01, c02 = c01 + p02, c03 = c02 + p03;
    float c10 = p10, c11 = c10 + p11, c12 = c11 + p12, c13 = c12 + p13;
    float c20 = p20, c21 = c20 + p21, c22 = c21 + p22, c23 = c22 + p23;
    float c30 = p30, c31 = c30 + p31, c32 = c31 + p32, c33 = c32 + p33;

    // wave inclusive scans of the 4 group sums
    float g0 = c03, g1 = c13, g2 = c23, g3 = c33;
    float i0 = g0, i1 = g1, i2 = g2, i3 = g3;
#pragma unroll
    for (int off = 1; off < 64; off <<= 1) {
        float v0 = __shfl_up(i0, off), v1 = __shfl_up(i1, off);
        float v2 = __shfl_up(i2, off), v3 = __shfl_up(i3, off);
        if (lane >= off) { i0 += v0; i1 += v1; i2 += v2; i3 += v3; }
    }
    float tot0 = __shfl(i0, 63), tot1 = __shfl(i1, 63), tot2 = __shfl(i2, 63);
    float ex0 = __shfl_up(i0, 1), ex1 = __shfl_up(i1, 1),
          ex2 = __shfl_up(i2, 1), ex3 = __shfl_up(i3, 1);
    if (lane == 0) { ex0 = 0.f; ex1 = 0.f; ex2 = 0.f; ex3 = 0.f; }
    float J1 = tot0, J2 = J1 + tot1, J3 = J2 + tot2;
    float b0 = ex0;            // J0 = 0
    float b1 = J1 + ex1;
    float b2 = J2 + ex2;
    float b3 = J3 + ex3;

    // ---- first index with cumsum >= u == count of (cumsum < u) ----
    const float u = u_mult[t];
    int cnt = (int)(b0 + c00 < u) + (int)(b0 + c01 < u) + (int)(b0 + c02 < u) + (int)(b0 + c03 < u)
            + (int)(b1 + c10 < u) + (int)(b1 + c11 < u) + (int)(b1 + c12 < u) + (int)(b1 + c13 < u)
            + (int)(b2 + c20 < u) + (int)(b2 + c21 < u) + (int)(b2 + c22 < u) + (int)(b2 + c23 < u)
            + (int)(b3 + c30 < u) + (int)(b3 + c31 < u) + (int)(b3 + c32 < u) + (int)(b3 + c33 < u);
    cnt = waveSumI(cnt);

    if (lane == 0) {
        int idx = (cnt >= N_NEUR) ? 0 : cnt;   // all-False -> argmax returns 0
        idx_ws[t] = idx;
        float log_total = my + logf(sum_ey);
        thr_out[t] = (log_total + (float)(-6.907755278982137)) - logf(rand_val[t]);
    }
}

// ---------------- sequential inhibition recurrence, LDS-resident fixpoint ----
// thr staged once into LDS [i][c] (stride 257 -> conflict-free). Jacobi rounds
// on chunk-boundary states touch only LDS+registers. Exactness propagates >=1
// chunk per round, so 258 rounds is provably exact; contraction (0.8187^128
// ~ 8e-12) makes ~4 rounds the expected case. Final pass overwrites LDS with
// inh (spike flag in sign bit; valid since post-spike inh >= 3000 > 0), then
// one coalesced write-out with the sparse one-hot scatter folded in.
__global__ __launch_bounds__(256) void scan_kernel(
    const float* __restrict__ thr, const int* __restrict__ idx_ws,
    float* __restrict__ inh_out, float* __restrict__ out_spikes)
{
    __shared__ float lds[CHUNK * LDS_STRIDE];   // 128 * 257 * 4 = 131584 B
    __shared__ float bnd[NCHUNK + 1];
    __shared__ int   s_any;

    const int tid = threadIdx.x;
    const float F = 0.8187307530779818f;        // (float)exp(-DT/INH_TAU)

    for (int t = tid; t < T_STEPS; t += 256)
        lds[(t & (CHUNK - 1)) * LDS_STRIDE + (t >> 7)] = thr[t];
    if (tid == 0) { bnd[0] = 0.f; s_any = 0; }
    bnd[tid + 1] = 0.f;
    __syncthreads();

    for (int round = 0; round < NCHUNK + 2; ++round) {
        float inh = bnd[tid];
#pragma unroll 8
        for (int i = 0; i < CHUNK; ++i) {
            float th = lds[i * LDS_STRIDE + tid];
            bool spike = inh < th;
            inh = __fmul_rn(inh, F);
            inh = __fadd_rn(inh, spike ? 3000.0f : 0.0f);   // +0.0 is exact identity (inh >= 0)
        }
        int ch = (__float_as_uint(inh) != __float_as_uint(bnd[tid + 1]));
        __syncthreads();                        // SYNC_A: all bnd reads done
        bnd[tid + 1] = inh;
        if (ch) s_any = 1;
        __syncthreads();                        // SYNC_B: flag/bnd writes visible
        int any = s_any;
        __syncthreads();                        // SYNC_C: reads done before reset
        if (tid == 0) s_any = 0;
        if (!any) break;
    }

    // final exact pass: overwrite lds with inh, spike in sign bit
    {
        float inh = bnd[tid];
#pragma unroll 8
        for (int i = 0; i < CHUNK; ++i) {
            float th = lds[i * LDS_STRIDE + tid];
            bool spike = inh < th;
            inh = __fmul_rn(inh, F);
            inh = __fadd_rn(inh, spike ? 3000.0f : 0.0f);
            lds[i * LDS_STRIDE + tid] =
                spike ? __uint_as_float(__float_as_uint(inh) | 0x80000000u) : inh;
        }
    }
    __syncthreads();

    // coalesced write-out + sparse one-hot scatter (~800 spikes total)
    for (int t = tid; t < T_STEPS; t += 256) {
        unsigned v = __float_as_uint(lds[(t & (CHUNK - 1)) * LDS_STRIDE + (t >> 7)]);
        inh_out[t] = __uint_as_float(v & 0x7fffffffu);
        if (v >> 31)
            out_spikes[(size_t)t * N_NEUR + idx_ws[t]] = 1.0f;
    }
}

extern "C" void kernel_launch(void* const* d_in, const int* in_sizes, int n_in,
                              void* d_out, int out_size, void* d_ws, size_t ws_size,
                              hipStream_t stream)
{
    const float* inputs     = (const float*)d_in[0];
    const float* noise_rand = (const float*)d_in[1];
    const float* u_mult     = (const float*)d_in[2];
    const float* rand_val   = (const float*)d_in[3];

    float* out_spk   = (float*)d_out;
    float* out_inh   = out_spk + (size_t)T_STEPS * N_NEUR;
    float* out_noise = out_inh + T_STEPS;

    float* thr_ws = (float*)d_ws;
    int*   idx_ws = (int*)((char*)d_ws + (size_t)T_STEPS * 4);

    noise_kernel<<<T_STEPS / 256, 256, 0, stream>>>(noise_rand, out_noise);
    rows_kernel<<<T_STEPS / 4, 256, 0, stream>>>(inputs, out_noise, u_mult, rand_val,
                                                 out_spk, thr_ws, idx_ws);
    scan_kernel<<<1, 256, 0, stream>>>(thr_ws, idx_ws, out_inh, out_spk);
}

// Round 5
// 340.171 us; speedup vs baseline: 1.9588x; 1.1186x over previous
//
#include <hip/hip_runtime.h>
#include <math.h>

#define T_STEPS 32768
#define N_NEUR  1024
#define FILT_LEN 200
#define CHUNK   128          // scan steps per chunk
#define NCHUNK  256          // chunks (= block size of scan kernel)
#define LDS_STRIDE 257       // [i][c] row stride, +1 pad -> bank-conflict-free

typedef float f32x4 __attribute__((ext_vector_type(4)));  // native vector: OK for nontemporal builtins

__device__ __forceinline__ float waveMax(float v) {
#pragma unroll
    for (int off = 32; off > 0; off >>= 1) v = fmaxf(v, __shfl_xor(v, off));
    return v;
}
__device__ __forceinline__ float waveSum(float v) {
#pragma unroll
    for (int off = 32; off > 0; off >>= 1) v += __shfl_xor(v, off);
    return v;
}
__device__ __forceinline__ int waveSumI(int v) {
#pragma unroll
    for (int off = 32; off > 0; off >>= 1) v += __shfl_xor(v, off);
    return v;
}

// ---------------- noise: 200-tap causal FIR of noise_rand*0.2 ----------------
__global__ __launch_bounds__(256) void noise_kernel(
    const float* __restrict__ noise_rand, float* __restrict__ noise_out)
{
    __shared__ float s_filt[FILT_LEN];
    __shared__ float s_nr[256 + FILT_LEN - 1];
    const int tid = threadIdx.x;
    const int t0  = blockIdx.x * 256;

    if (tid < FILT_LEN) s_filt[tid] = expf(-((float)tid * 0.05f));
    for (int i = tid; i < 256 + FILT_LEN - 1; i += 256) {
        int k = t0 - (FILT_LEN - 1) + i;
        s_nr[i] = (k >= 0) ? noise_rand[k] * 0.2f : 0.0f;
    }
    __syncthreads();

    const int t = t0 + tid;
    float acc = 0.0f;
#pragma unroll 4
    for (int j = FILT_LEN - 1; j >= 0; --j) {
        acc = fmaf(s_nr[tid + (FILT_LEN - 1) - j], s_filt[j], acc);
    }
    noise_out[t] = acc;
}

// ---------------- per-row (one WAVE per row): softmax-cumsum argmax + thr ----
// NUMERICS FROZEN (passed round 3, absmax 4.9e-4): element order, op order and
// reduction tree shapes must not change. Only nontemporal hints added
// (f32x4 native vector type; value-identical to the float4 path).
__global__ __launch_bounds__(256) void rows_kernel(
    const float* __restrict__ inputs, const float* __restrict__ noise,
    const float* __restrict__ u_mult, const float* __restrict__ rand_val,
    float* __restrict__ out_spikes, float* __restrict__ thr_out,
    int* __restrict__ idx_ws)
{
    const int wid  = threadIdx.x >> 6;
    const int lane = threadIdx.x & 63;
    const int t    = blockIdx.x * 4 + wid;

    const f32x4* row = reinterpret_cast<const f32x4*>(inputs + (size_t)t * N_NEUR);
    f32x4 x0 = __builtin_nontemporal_load(&row[lane]);
    f32x4 x1 = __builtin_nontemporal_load(&row[lane + 64]);
    f32x4 x2 = __builtin_nontemporal_load(&row[lane + 128]);
    f32x4 x3 = __builtin_nontemporal_load(&row[lane + 192]);

    // zero-fill this output row (harness poisons d_out); sparse scatter later
    f32x4 z = (f32x4){0.f, 0.f, 0.f, 0.f};
    f32x4* orow = reinterpret_cast<f32x4*>(out_spikes + (size_t)t * N_NEUR);
    __builtin_nontemporal_store(z, &orow[lane]);
    __builtin_nontemporal_store(z, &orow[lane + 64]);
    __builtin_nontemporal_store(z, &orow[lane + 128]);
    __builtin_nontemporal_store(z, &orow[lane + 192]);

    // ---- row max ----
    float m = fmaxf(
        fmaxf(fmaxf(fmaxf(x0[0], x0[1]), fmaxf(x0[2], x0[3])),
              fmaxf(fmaxf(x1[0], x1[1]), fmaxf(x1[2], x1[3]))),
        fmaxf(fmaxf(fmaxf(x2[0], x2[1]), fmaxf(x2[2], x2[3])),
              fmaxf(fmaxf(x3[0], x3[1]), fmaxf(x3[2], x3[3]))));
    m = waveMax(m);

    // ---- softmax numerators (no noise) + denominator ----
    float e00 = expf(x0[0] - m), e01 = expf(x0[1] - m), e02 = expf(x0[2] - m), e03 = expf(x0[3] - m);
    float e10 = expf(x1[0] - m), e11 = expf(x1[1] - m), e12 = expf(x1[2] - m), e13 = expf(x1[3] - m);
    float e20 = expf(x2[0] - m), e21 = expf(x2[1] - m), e22 = expf(x2[2] - m), e23 = expf(x2[3] - m);
    float e30 = expf(x3[0] - m), e31 = expf(x3[1] - m), e32 = expf(x3[2] - m), e33 = expf(x3[3] - m);
    float s0 = ((e00 + e01) + e02) + e03;
    float s1 = ((e10 + e11) + e12) + e13;
    float s2 = ((e20 + e21) + e22) + e23;
    float s3 = ((e30 + e31) + e32) + e33;
    const float sum_e = waveSum(((s0 + s1) + s2) + s3);

    // ---- logsumexp over y = x + noise; max(y) = fl(m + nz) by monotonicity ----
    const float nz = noise[t];
    const float my = m + nz;
    float f0 = ((expf((x0[0] + nz) - my) + expf((x0[1] + nz) - my))
              +  expf((x0[2] + nz) - my)) + expf((x0[3] + nz) - my);
    float f1 = ((expf((x1[0] + nz) - my) + expf((x1[1] + nz) - my))
              +  expf((x1[2] + nz) - my)) + expf((x1[3] + nz) - my);
    float f2 = ((expf((x2[0] + nz) - my) + expf((x2[1] + nz) - my))
              +  expf((x2[2] + nz) - my)) + expf((x2[3] + nz) - my);
    float f3 = ((expf((x3[0] + nz) - my) + expf((x3[1] + nz) - my))
              +  expf((x3[2] + nz) - my)) + expf((x3[3] + nz) - my);
    const float sum_ey = waveSum(((f0 + f1) + f2) + f3);

    // ---- p = e / sum_e (true division, per reference), hierarchical prefix ----
    float p00 = e00 / sum_e, p01 = e01 / sum_e, p02 = e02 / sum_e, p03 = e03 / sum_e;
    float p10 = e10 / sum_e, p11 = e11 / sum_e, p12 = e12 / sum_e, p13 = e13 / sum_e;
    float p20 = e20 / sum_e, p21 = e21 / sum_e, p22 = e22 / sum_e, p23 = e23 / sum_e;
    float p30 = e30 / sum_e, p31 = e31 / sum_e, p32 = e32 / sum_e, p33 = e33 / sum_e;

    // within-group prefixes
    float c00 = p00, c01 = c00 + p01, c02 = c01 + p02, c03 = c02 + p03;
    float c10 = p10, c11 = c10 + p11, c12 = c11 + p12, c13 = c12 + p13;
    float c20 = p20, c21 = c20 + p21, c22 = c21 + p22, c23 = c22 + p23;
    float c30 = p30, c31 = c30 + p31, c32 = c31 + p32, c33 = c32 + p33;

    // wave inclusive scans of the 4 group sums
    float g0 = c03, g1 = c13, g2 = c23, g3 = c33;
    float i0 = g0, i1 = g1, i2 = g2, i3 = g3;
#pragma unroll
    for (int off = 1; off < 64; off <<= 1) {
        float v0 = __shfl_up(i0, off), v1 = __shfl_up(i1, off);
        float v2 = __shfl_up(i2, off), v3 = __shfl_up(i3, off);
        if (lane >= off) { i0 += v0; i1 += v1; i2 += v2; i3 += v3; }
    }
    float tot0 = __shfl(i0, 63), tot1 = __shfl(i1, 63), tot2 = __shfl(i2, 63);
    float ex0 = __shfl_up(i0, 1), ex1 = __shfl_up(i1, 1),
          ex2 = __shfl_up(i2, 1), ex3 = __shfl_up(i3, 1);
    if (lane == 0) { ex0 = 0.f; ex1 = 0.f; ex2 = 0.f; ex3 = 0.f; }
    float J1 = tot0, J2 = J1 + tot1, J3 = J2 + tot2;
    float b0 = ex0;            // J0 = 0
    float b1 = J1 + ex1;
    float b2 = J2 + ex2;
    float b3 = J3 + ex3;

    // ---- first index with cumsum >= u == count of (cumsum < u) ----
    const float u = u_mult[t];
    int cnt = (int)(b0 + c00 < u) + (int)(b0 + c01 < u) + (int)(b0 + c02 < u) + (int)(b0 + c03 < u)
            + (int)(b1 + c10 < u) + (int)(b1 + c11 < u) + (int)(b1 + c12 < u) + (int)(b1 + c13 < u)
            + (int)(b2 + c20 < u) + (int)(b2 + c21 < u) + (int)(b2 + c22 < u) + (int)(b2 + c23 < u)
            + (int)(b3 + c30 < u) + (int)(b3 + c31 < u) + (int)(b3 + c32 < u) + (int)(b3 + c33 < u);
    cnt = waveSumI(cnt);

    if (lane == 0) {
        int idx = (cnt >= N_NEUR) ? 0 : cnt;   // all-False -> argmax returns 0
        idx_ws[t] = idx;
        float log_total = my + logf(sum_ey);
        thr_out[t] = (log_total + (float)(-6.907755278982137)) - logf(rand_val[t]);
    }
}

// ---------------- sequential inhibition recurrence, REGISTER-resident -------
// thr staged global->LDS (coalesced) -> 128 registers per thread (static
// indices via full unroll). Jacobi rounds touch only registers + the 257-float
// bnd array; per-step dependent chain is cmp->cndmask (both next-state
// candidates precomputed off the critical path; bit-identical to the passing
// round-3 numerics since fl(a+0.0f)==a for a>=+0). Exactness propagates >=1
// chunk/round so the 258-round cap is provably exact; contraction makes ~10-25
// rounds the expected case. Final pass re-uses LDS for the transposed,
// coalesced write-out with the sparse one-hot scatter folded in.
__global__ __launch_bounds__(256, 1) void scan_kernel(
    const float* __restrict__ thr, const int* __restrict__ idx_ws,
    float* __restrict__ inh_out, float* __restrict__ out_spikes)
{
    __shared__ float lds[CHUNK * LDS_STRIDE];   // 128 * 257 * 4 = 131584 B
    __shared__ float bnd[NCHUNK + 1];
    __shared__ int   s_any;

    const int tid = threadIdx.x;
    const float F = 0.8187307530779818f;        // (float)exp(-DT/INH_TAU)

    for (int t = tid; t < T_STEPS; t += 256)
        lds[(t & (CHUNK - 1)) * LDS_STRIDE + (t >> 7)] = thr[t];
    if (tid == 0) { bnd[0] = 0.f; s_any = 0; }
    bnd[tid + 1] = 0.f;
    __syncthreads();

    // own chunk's thresholds -> registers (conflict-free column reads)
    float th[CHUNK];
#pragma unroll
    for (int i = 0; i < CHUNK; ++i) th[i] = lds[i * LDS_STRIDE + tid];

    for (int round = 0; round < NCHUNK + 2; ++round) {
        float inh = bnd[tid];
#pragma unroll
        for (int i = 0; i < CHUNK; ++i) {
            float a = __fmul_rn(inh, F);            // no-spike candidate
            float b = __fadd_rn(a, 3000.0f);        // spike candidate
            inh = (inh < th[i]) ? b : a;            // chain: cmp -> cndmask
        }
        int ch = (__float_as_uint(inh) != __float_as_uint(bnd[tid + 1]));
        __syncthreads();                        // SYNC_A: all bnd reads done
        bnd[tid + 1] = inh;
        if (ch) s_any = 1;
        __syncthreads();                        // SYNC_B: flag/bnd writes visible
        int any = s_any;
        __syncthreads();                        // SYNC_C: reads done before reset
        if (tid == 0) s_any = 0;
        if (!any) break;
    }

    // final exact pass: write inh into LDS column, spike flag in sign bit
    // (valid: post-spike inh >= 3000 > 0)
    {
        float inh = bnd[tid];
#pragma unroll
        for (int i = 0; i < CHUNK; ++i) {
            bool spike = inh < th[i];
            float a = __fmul_rn(inh, F);
            float b = __fadd_rn(a, 3000.0f);
            inh = spike ? b : a;
            lds[i * LDS_STRIDE + tid] =
                spike ? __uint_as_float(__float_as_uint(inh) | 0x80000000u) : inh;
        }
    }
    __syncthreads();

    // coalesced write-out + sparse one-hot scatter (~800 spikes total)
    for (int t = tid; t < T_STEPS; t += 256) {
        unsigned v = __float_as_uint(lds[(t & (CHUNK - 1)) * LDS_STRIDE + (t >> 7)]);
        inh_out[t] = __uint_as_float(v & 0x7fffffffu);
        if (v >> 31)
            out_spikes[(size_t)t * N_NEUR + idx_ws[t]] = 1.0f;
    }
}

extern "C" void kernel_launch(void* const* d_in, const int* in_sizes, int n_in,
                              void* d_out, int out_size, void* d_ws, size_t ws_size,
                              hipStream_t stream)
{
    const float* inputs     = (const float*)d_in[0];
    const float* noise_rand = (const float*)d_in[1];
    const float* u_mult     = (const float*)d_in[2];
    const float* rand_val   = (const float*)d_in[3];

    float* out_spk   = (float*)d_out;
    float* out_inh   = out_spk + (size_t)T_STEPS * N_NEUR;
    float* out_noise = out_inh + T_STEPS;

    float* thr_ws = (float*)d_ws;
    int*   idx_ws = (int*)((char*)d_ws + (size_t)T_STEPS * 4);

    noise_kernel<<<T_STEPS / 256, 256, 0, stream>>>(noise_rand, out_noise);
    rows_kernel<<<T_STEPS / 4, 256, 0, stream>>>(inputs, out_noise, u_mult, rand_val,
                                                 out_spk, thr_ws, idx_ws);
    scan_kernel<<<1, 256, 0, stream>>>(thr_ws, idx_ws, out_inh, out_spk);
}